// Round 1
// baseline (194.202 us; speedup 1.0000x reference)
//
#include <hip/hip_runtime.h>
#include <cstddef>

// Problem constants (from setup_inputs): B=16, J=1024, L=4096, D=512, fp32.
namespace {
constexpr int Bn = 16;
constexpr int Jn = 1024;
constexpr int Ln = 4096;
constexpr int Dn = 512;
constexpr int G  = 32;          // chunk length along J
constexpr int C  = Jn / G;      // 32 chunks
constexpr float kEps = 1e-4f;
}

// --- Kernel 1: per-(b,chunk) prefix products of A_j = mask ? (1-p) : 1 ---
// PA[b*J+j]  = prod of A from chunk start through j (inclusive)
// Ap[b*C+c]  = product over the whole chunk
__global__ void k_aprod(const float* __restrict__ conf, const int* __restrict__ mask,
                        float* __restrict__ PA, float* __restrict__ Ap) {
  int t = blockIdx.x * blockDim.x + threadIdx.x;
  if (t >= Bn * C) return;
  int b = t / C, c = t % C;
  int base = b * Jn + c * G;
  float prod = 1.0f;
  for (int i = 0; i < G; ++i) {
    float p = conf[base + i];
    p = fminf(fmaxf(p, kEps), 1.0f - kEps);
    float a = (mask[base + i] != 0) ? (1.0f - p) : 1.0f;
    prod *= a;
    PA[base + i] = prod;
  }
  Ap[t] = prod;
}

// --- Kernel 2: boundary cumsum -> gather index idx[b,l] = clip(cumsum-1, 0, J-1) ---
__global__ void k_idx(const int* __restrict__ bnd, int* __restrict__ idx) {
  int b = blockIdx.x;
  int t = threadIdx.x;                 // 256 threads
  const int per = Ln / 256;            // 16 elements per thread
  const int* row = bnd + (size_t)b * Ln;
  int s = 0;
#pragma unroll
  for (int i = 0; i < per; ++i) s += (row[t * per + i] != 0) ? 1 : 0;

  __shared__ int sh[256];
  sh[t] = s;
  __syncthreads();
  // Hillis-Steele inclusive scan over 256 entries
  for (int off = 1; off < 256; off <<= 1) {
    int v = (t >= off) ? sh[t - off] : 0;
    __syncthreads();
    sh[t] += v;
    __syncthreads();
  }
  int run = sh[t] - s;                 // exclusive prefix
#pragma unroll
  for (int i = 0; i < per; ++i) {
    run += (row[t * per + i] != 0) ? 1 : 0;
    int v = run - 1;
    v = v < 0 ? 0 : (v > Jn - 1 ? Jn - 1 : v);
    idx[(size_t)b * Ln + t * per + i] = v;
  }
}

// --- Kernel 3: chunk-local scan (zero init), store chunk-end values E[b,c,d] ---
// block = (b,c), 128 threads, each thread one float4 of D
__global__ void k_chunk_end(const float* __restrict__ emb, const float* __restrict__ conf,
                            const int* __restrict__ mask, float* __restrict__ E) {
  int bc = blockIdx.x;
  int b = bc / C, c = bc % C;
  int d4 = threadIdx.x;                // 0..127
  float4 s = make_float4(0.f, 0.f, 0.f, 0.f);
  for (int i = 0; i < G; ++i) {
    int j = c * G + i;
    float p = conf[b * Jn + j];
    p = fminf(fmaxf(p, kEps), 1.0f - kEps);
    bool m = (mask[b * Jn + j] != 0);
    float4 e = ((const float4*)(emb + ((size_t)(b * Jn + j)) * Dn))[d4];
    if (m) {
      float q = 1.0f - p;
      s.x = p * e.x + q * s.x;
      s.y = p * e.y + q * s.y;
      s.z = p * e.z + q * s.z;
      s.w = p * e.w + q * s.w;
    }
  }
  ((float4*)(E + (size_t)bc * Dn))[d4] = s;
}

// --- Kernel 4: cross-chunk recurrence: S[b,c,d] = value entering chunk c ---
__global__ void k_chunk_start(const float* __restrict__ E, const float* __restrict__ Ap,
                              float* __restrict__ S) {
  int t = blockIdx.x * blockDim.x + threadIdx.x;   // over B * D/4
  if (t >= Bn * (Dn / 4)) return;
  int b = t / (Dn / 4), d4 = t % (Dn / 4);
  float4 s = make_float4(0.f, 0.f, 0.f, 0.f);
  for (int c = 0; c < C; ++c) {
    ((float4*)(S + ((size_t)(b * C + c)) * Dn))[d4] = s;
    float a = Ap[b * C + c];
    float4 e = ((const float4*)(E + ((size_t)(b * C + c)) * Dn))[d4];
    s.x = e.x + a * s.x;
    s.y = e.y + a * s.y;
    s.z = e.z + a * s.z;
    s.w = e.w + a * s.w;
  }
}

// --- Kernel 5: materialize smoothed[b,j,d] = local_scan + PA[b,j] * S[b,c,d] ---
__global__ void k_smooth(const float* __restrict__ emb, const float* __restrict__ conf,
                         const int* __restrict__ mask, const float* __restrict__ PA,
                         const float* __restrict__ S, float* __restrict__ smoothed) {
  int bc = blockIdx.x;
  int b = bc / C, c = bc % C;
  int d4 = threadIdx.x;                // 0..127
  float4 s = make_float4(0.f, 0.f, 0.f, 0.f);
  float4 sc = ((const float4*)(S + (size_t)bc * Dn))[d4];
  for (int i = 0; i < G; ++i) {
    int j = c * G + i;
    float p = conf[b * Jn + j];
    p = fminf(fmaxf(p, kEps), 1.0f - kEps);
    bool m = (mask[b * Jn + j] != 0);
    float4 e = ((const float4*)(emb + ((size_t)(b * Jn + j)) * Dn))[d4];
    if (m) {
      float q = 1.0f - p;
      s.x = p * e.x + q * s.x;
      s.y = p * e.y + q * s.y;
      s.z = p * e.z + q * s.z;
      s.w = p * e.w + q * s.w;
    }
    float pa = PA[b * Jn + j];
    float4 o;
    o.x = s.x + pa * sc.x;
    o.y = s.y + pa * sc.y;
    o.z = s.z + pa * sc.z;
    o.w = s.w + pa * sc.w;
    ((float4*)(smoothed + ((size_t)(b * Jn + j)) * Dn))[d4] = o;
  }
}

// --- Kernel 6: gather upsample: frames[b,l,:] = smoothed[b, idx[b,l], :] ---
__global__ void k_gather(const float* __restrict__ smoothed, const int* __restrict__ idx,
                         float* __restrict__ out) {
  size_t tid = (size_t)blockIdx.x * blockDim.x + threadIdx.x;  // over B*L*(D/4)
  int d4 = (int)(tid & (Dn / 4 - 1));        // 0..127
  size_t bl = tid >> 7;                      // b*L + l
  int j = idx[bl];                           // wave-uniform (64 lanes share one l)
  size_t b = bl >> 12;                       // L = 4096
  float4 v = ((const float4*)(smoothed + (b * Jn + (size_t)j) * Dn))[d4];
  ((float4*)out)[tid] = v;
}

extern "C" void kernel_launch(void* const* d_in, const int* in_sizes, int n_in,
                              void* d_out, int out_size, void* d_ws, size_t ws_size,
                              hipStream_t stream) {
  const float* emb  = (const float*)d_in[0];   // B*J*D fp32
  const float* conf = (const float*)d_in[1];   // B*J fp32
  const int*   mask = (const int*)d_in[2];     // B*J bool -> int
  const int*   bnd  = (const int*)d_in[3];     // B*L bool -> int
  float* out = (float*)d_out;                  // B*L*D fp32

  float* ws = (float*)d_ws;
  float* smoothed = ws;                                  // B*J*D   (8,388,608 f)
  float* E   = smoothed + (size_t)Bn * Jn * Dn;          // B*C*D   (262,144 f)
  float* S   = E + (size_t)Bn * C * Dn;                  // B*C*D   (262,144 f)
  float* PA  = S + (size_t)Bn * C * Dn;                  // B*J     (16,384 f)
  float* Ap  = PA + (size_t)Bn * Jn;                     // B*C     (512 f)
  int*   idx = (int*)(Ap + Bn * C);                      // B*L     (65,536 i)

  hipLaunchKernelGGL(k_aprod, dim3((Bn * C + 255) / 256), dim3(256), 0, stream,
                     conf, mask, PA, Ap);
  hipLaunchKernelGGL(k_idx, dim3(Bn), dim3(256), 0, stream, bnd, idx);
  hipLaunchKernelGGL(k_chunk_end, dim3(Bn * C), dim3(Dn / 4), 0, stream,
                     emb, conf, mask, E);
  hipLaunchKernelGGL(k_chunk_start, dim3((Bn * (Dn / 4) + 255) / 256), dim3(256), 0, stream,
                     E, Ap, S);
  hipLaunchKernelGGL(k_smooth, dim3(Bn * C), dim3(Dn / 4), 0, stream,
                     emb, conf, mask, PA, S, smoothed);
  size_t total4 = (size_t)Bn * Ln * (Dn / 4);
  hipLaunchKernelGGL(k_gather, dim3((unsigned)(total4 / 256)), dim3(256), 0, stream,
                     smoothed, idx, out);
}

// Round 2
// 187.600 us; speedup vs baseline: 1.0352x; 1.0352x over previous
//
#include <hip/hip_runtime.h>
#include <cstddef>

// Problem constants (from setup_inputs): B=16, J=1024, L=4096, D=512, fp32.
namespace {
constexpr int Bn = 16;
constexpr int Jn = 1024;
constexpr int Ln = 4096;
constexpr int Dn = 512;
constexpr int G  = 32;          // chunk length along J
constexpr int C  = Jn / G;      // 32 chunks
constexpr float kEps = 1e-4f;
}

// --- Kernel 1: boundary cumsum -> gather index idx[b,l] = clip(cumsum-1, 0, J-1) ---
__global__ void k_idx(const int* __restrict__ bnd, int* __restrict__ idx) {
  int b = blockIdx.x;
  int t = threadIdx.x;                 // 256 threads
  const int per = Ln / 256;            // 16 elements per thread
  const int* row = bnd + (size_t)b * Ln;
  int s = 0;
#pragma unroll
  for (int i = 0; i < per; ++i) s += (row[t * per + i] != 0) ? 1 : 0;

  __shared__ int sh[256];
  sh[t] = s;
  __syncthreads();
  for (int off = 1; off < 256; off <<= 1) {
    int v = (t >= off) ? sh[t - off] : 0;
    __syncthreads();
    sh[t] += v;
    __syncthreads();
  }
  int run = sh[t] - s;                 // exclusive prefix
#pragma unroll
  for (int i = 0; i < per; ++i) {
    run += (row[t * per + i] != 0) ? 1 : 0;
    int v = run - 1;
    v = v < 0 ? 0 : (v > Jn - 1 ? Jn - 1 : v);
    idx[(size_t)b * Ln + t * per + i] = v;
  }
}

// --- Kernel 2: one pass over emb. Per (b,chunk): chunk-local EMA scan with zero
// init -> write UNCORRECTED local[b,j,d], chunk-end E[b,c,d], and the A-prefix
// products PA[b,j] / chunk product Ap[b,c] (computed redundantly per thread,
// written by thread 0 — conf/mask are read anyway).
__global__ void k_pass1(const float* __restrict__ emb, const float* __restrict__ conf,
                        const int* __restrict__ mask, float* __restrict__ local,
                        float* __restrict__ E, float* __restrict__ PA,
                        float* __restrict__ Ap) {
  int bc = blockIdx.x;
  int b = bc / C, c = bc % C;
  int d4 = threadIdx.x;                // 0..127
  int base = b * Jn + c * G;
  float4 s = make_float4(0.f, 0.f, 0.f, 0.f);
  float prod = 1.0f;
  for (int i = 0; i < G; ++i) {
    int j = base + i;
    float p = conf[j];
    p = fminf(fmaxf(p, kEps), 1.0f - kEps);
    bool m = (mask[j] != 0);
    float q = 1.0f - p;
    float4 e = ((const float4*)(emb + (size_t)j * Dn))[d4];
    if (m) {
      s.x = p * e.x + q * s.x;
      s.y = p * e.y + q * s.y;
      s.z = p * e.z + q * s.z;
      s.w = p * e.w + q * s.w;
      prod *= q;
    }
    ((float4*)(local + (size_t)j * Dn))[d4] = s;
    if (d4 == 0) PA[j] = prod;
  }
  ((float4*)(E + (size_t)bc * Dn))[d4] = s;
  if (d4 == 0) Ap[bc] = prod;
}

// --- Kernel 3: cross-chunk recurrence: S[b,c,d] = value entering chunk c ---
__global__ void k_chunk_start(const float* __restrict__ E, const float* __restrict__ Ap,
                              float* __restrict__ S) {
  int t = blockIdx.x * blockDim.x + threadIdx.x;   // over B * D/4
  if (t >= Bn * (Dn / 4)) return;
  int b = t / (Dn / 4), d4 = t % (Dn / 4);
  float4 s = make_float4(0.f, 0.f, 0.f, 0.f);
  for (int c = 0; c < C; ++c) {
    ((float4*)(S + ((size_t)(b * C + c)) * Dn))[d4] = s;
    float a = Ap[b * C + c];
    float4 e = ((const float4*)(E + ((size_t)(b * C + c)) * Dn))[d4];
    s.x = e.x + a * s.x;
    s.y = e.y + a * s.y;
    s.z = e.z + a * s.z;
    s.w = e.w + a * s.w;
  }
}

// --- Kernel 4: fused correction + gather upsample:
// frames[b,l,:] = local[b,j,:] + PA[b,j] * S[b, j/G, :],  j = idx[b,l]
__global__ void k_gather(const float* __restrict__ local, const float* __restrict__ PA,
                         const float* __restrict__ S, const int* __restrict__ idx,
                         float* __restrict__ out) {
  size_t tid = (size_t)blockIdx.x * blockDim.x + threadIdx.x;  // over B*L*(D/4)
  int d4 = (int)(tid & (Dn / 4 - 1));        // 0..127
  size_t bl = tid >> 7;                      // b*L + l
  int j = idx[bl];                           // wave-uniform (64 lanes share one l)
  size_t b = bl >> 12;                       // L = 4096
  int c = j >> 5;                            // chunk of j
  float pa = PA[b * Jn + (size_t)j];
  float4 sc = ((const float4*)(S + (b * C + (size_t)c) * Dn))[d4];
  float4 lo = ((const float4*)(local + (b * Jn + (size_t)j) * Dn))[d4];
  float4 o;
  o.x = lo.x + pa * sc.x;
  o.y = lo.y + pa * sc.y;
  o.z = lo.z + pa * sc.z;
  o.w = lo.w + pa * sc.w;
  ((float4*)out)[tid] = o;
}

extern "C" void kernel_launch(void* const* d_in, const int* in_sizes, int n_in,
                              void* d_out, int out_size, void* d_ws, size_t ws_size,
                              hipStream_t stream) {
  const float* emb  = (const float*)d_in[0];   // B*J*D fp32
  const float* conf = (const float*)d_in[1];   // B*J fp32
  const int*   mask = (const int*)d_in[2];     // B*J bool -> int
  const int*   bnd  = (const int*)d_in[3];     // B*L bool -> int
  float* out = (float*)d_out;                  // B*L*D fp32

  float* ws = (float*)d_ws;
  float* local = ws;                                     // B*J*D   (8,388,608 f)
  float* E   = local + (size_t)Bn * Jn * Dn;             // B*C*D   (262,144 f)
  float* S   = E + (size_t)Bn * C * Dn;                  // B*C*D   (262,144 f)
  float* PA  = S + (size_t)Bn * C * Dn;                  // B*J     (16,384 f)
  float* Ap  = PA + (size_t)Bn * Jn;                     // B*C     (512 f)
  int*   idx = (int*)(Ap + Bn * C);                      // B*L     (65,536 i)

  hipLaunchKernelGGL(k_idx, dim3(Bn), dim3(256), 0, stream, bnd, idx);
  hipLaunchKernelGGL(k_pass1, dim3(Bn * C), dim3(Dn / 4), 0, stream,
                     emb, conf, mask, local, E, PA, Ap);
  hipLaunchKernelGGL(k_chunk_start, dim3((Bn * (Dn / 4) + 255) / 256), dim3(256), 0, stream,
                     E, Ap, S);
  size_t total4 = (size_t)Bn * Ln * (Dn / 4);
  hipLaunchKernelGGL(k_gather, dim3((unsigned)(total4 / 256)), dim3(256), 0, stream,
                     local, PA, S, idx, out);
}

// Round 3
// 180.366 us; speedup vs baseline: 1.0767x; 1.0401x over previous
//
#include <hip/hip_runtime.h>
#include <cstddef>

// Problem constants (from setup_inputs): B=16, J=1024, L=4096, D=512, fp32.
namespace {
constexpr int Bn = 16;
constexpr int Jn = 1024;
constexpr int Ln = 4096;
constexpr int Dn = 512;
constexpr int G  = 32;          // chunk length along J
constexpr int C  = Jn / G;      // 32 chunks
constexpr float kEps = 1e-4f;
constexpr int PASS1_BLOCKS = Bn * C;  // 512
}

// --- Kernel 1 (fused): blocks [0,512): per-(b,chunk) local EMA scan writing
// UNCORRECTED local[b,j,d], chunk-end E, A-prefix PA/Ap.
// Blocks [512,528): per-batch boundary cumsum -> gather index idx[b,l].
// Block-uniform branch; both sides use 128 threads.
__global__ __launch_bounds__(128) void k_fused1(
    const float* __restrict__ emb, const float* __restrict__ conf,
    const int* __restrict__ mask, const int* __restrict__ bnd,
    float* __restrict__ local, float* __restrict__ E,
    float* __restrict__ PA, float* __restrict__ Ap, int* __restrict__ idx) {
  int blk = blockIdx.x;
  int t = threadIdx.x;                 // 0..127
  if (blk < PASS1_BLOCKS) {
    int b = blk / C, c = blk % C;
    int base = b * Jn + c * G;
    float4 s = make_float4(0.f, 0.f, 0.f, 0.f);
    float prod = 1.0f;
#pragma unroll 8
    for (int i = 0; i < G; ++i) {
      int j = base + i;
      float p = conf[j];
      p = fminf(fmaxf(p, kEps), 1.0f - kEps);
      bool m = (mask[j] != 0);
      float q = 1.0f - p;
      float4 e = ((const float4*)(emb + (size_t)j * Dn))[t];
      if (m) {
        s.x = p * e.x + q * s.x;
        s.y = p * e.y + q * s.y;
        s.z = p * e.z + q * s.z;
        s.w = p * e.w + q * s.w;
        prod *= q;
      }
      ((float4*)(local + (size_t)j * Dn))[t] = s;
      if (t == 0) PA[j] = prod;
    }
    ((float4*)(E + (size_t)blk * Dn))[t] = s;
    if (t == 0) Ap[blk] = prod;
  } else {
    int b = blk - PASS1_BLOCKS;
    const int per = Ln / 128;          // 32 elements per thread
    const int* row = bnd + (size_t)b * Ln;
    int s = 0;
#pragma unroll 8
    for (int i = 0; i < per; ++i) s += (row[t * per + i] != 0) ? 1 : 0;

    __shared__ int sh[128];
    sh[t] = s;
    __syncthreads();
    for (int off = 1; off < 128; off <<= 1) {
      int v = (t >= off) ? sh[t - off] : 0;
      __syncthreads();
      sh[t] += v;
      __syncthreads();
    }
    int run = sh[t] - s;               // exclusive prefix
#pragma unroll 8
    for (int i = 0; i < per; ++i) {
      run += (row[t * per + i] != 0) ? 1 : 0;
      int v = run - 1;
      v = v < 0 ? 0 : (v > Jn - 1 ? Jn - 1 : v);
      idx[(size_t)b * Ln + t * per + i] = v;
    }
  }
}

// --- Kernel 2: cross-chunk recurrence: S[b,c,d] = value entering chunk c.
// Loads of E/Ap are chain-independent; partial unroll lets them batch.
__global__ __launch_bounds__(64) void k_chunk_start(
    const float* __restrict__ E, const float* __restrict__ Ap,
    float* __restrict__ S) {
  int tg = blockIdx.x * 64 + threadIdx.x;          // over B * D/4 = 2048
  int b = tg / (Dn / 4), d4 = tg % (Dn / 4);
  float4 s = make_float4(0.f, 0.f, 0.f, 0.f);
#pragma unroll 8
  for (int c = 0; c < C; ++c) {
    ((float4*)(S + ((size_t)(b * C + c)) * Dn))[d4] = s;
    float a = Ap[b * C + c];
    float4 e = ((const float4*)(E + ((size_t)(b * C + c)) * Dn))[d4];
    s.x = e.x + a * s.x;
    s.y = e.y + a * s.y;
    s.z = e.z + a * s.z;
    s.w = e.w + a * s.w;
  }
}

// --- Kernel 3: fused correction + gather upsample, XCD-swizzled.
// frames[b,l,:] = local[b,j,:] + PA[b,j] * S[b, j/G, :],  j = idx[b,l].
// Swizzle: round-robin block->XCD dispatch means (bid&7) selects the XCD;
// giving each XCD a contiguous sb-span keeps its gathered `local` rows
// (~4 MB/span, idx monotone in l) resident in that XCD's private L2.
__global__ __launch_bounds__(256) void k_gather(
    const float* __restrict__ local, const float* __restrict__ PA,
    const float* __restrict__ S, const int* __restrict__ idx,
    float* __restrict__ out) {
  unsigned bid = blockIdx.x;                         // 0..32767
  unsigned sb = (bid & 7u) * 4096u + (bid >> 3);     // bijection on [0,32768)
  size_t tid = (size_t)sb * 256 + threadIdx.x;       // over B*L*(D/4)
  int d4 = (int)(tid & (Dn / 4 - 1));                // 0..127
  size_t bl = tid >> 7;                              // b*L + l
  int j = idx[bl];                                   // wave-uniform
  size_t b = bl >> 12;                               // L = 4096
  int c = j >> 5;                                    // chunk of j
  float pa = PA[b * Jn + (size_t)j];
  float4 sc = ((const float4*)(S + (b * C + (size_t)c) * Dn))[d4];
  float4 lo = ((const float4*)(local + (b * Jn + (size_t)j) * Dn))[d4];
  float4 o;
  o.x = lo.x + pa * sc.x;
  o.y = lo.y + pa * sc.y;
  o.z = lo.z + pa * sc.z;
  o.w = lo.w + pa * sc.w;
  ((float4*)out)[tid] = o;
}

extern "C" void kernel_launch(void* const* d_in, const int* in_sizes, int n_in,
                              void* d_out, int out_size, void* d_ws, size_t ws_size,
                              hipStream_t stream) {
  const float* emb  = (const float*)d_in[0];   // B*J*D fp32
  const float* conf = (const float*)d_in[1];   // B*J fp32
  const int*   mask = (const int*)d_in[2];     // B*J bool -> int
  const int*   bnd  = (const int*)d_in[3];     // B*L bool -> int
  float* out = (float*)d_out;                  // B*L*D fp32

  float* ws = (float*)d_ws;
  float* local = ws;                                     // B*J*D   (8,388,608 f)
  float* E   = local + (size_t)Bn * Jn * Dn;             // B*C*D   (262,144 f)
  float* S   = E + (size_t)Bn * C * Dn;                  // B*C*D   (262,144 f)
  float* PA  = S + (size_t)Bn * C * Dn;                  // B*J     (16,384 f)
  float* Ap  = PA + (size_t)Bn * Jn;                     // B*C     (512 f)
  int*   idx = (int*)(Ap + Bn * C);                      // B*L     (65,536 i)

  hipLaunchKernelGGL(k_fused1, dim3(PASS1_BLOCKS + Bn), dim3(128), 0, stream,
                     emb, conf, mask, bnd, local, E, PA, Ap, idx);
  hipLaunchKernelGGL(k_chunk_start, dim3(Bn * (Dn / 4) / 64), dim3(64), 0, stream,
                     E, Ap, S);
  size_t total4 = (size_t)Bn * Ln * (Dn / 4);
  hipLaunchKernelGGL(k_gather, dim3((unsigned)(total4 / 256)), dim3(256), 0, stream,
                     local, PA, S, idx, out);
}